// Round 6
// baseline (674.441 us; speedup 1.0000x reference)
//
#include <hip/hip_runtime.h>
#include <hip/hip_bf16.h>

typedef __attribute__((ext_vector_type(8))) short short8;
typedef __attribute__((ext_vector_type(4))) float f32x4;

union B4 { __hip_bfloat16 h[4]; uint2 v; };
union B8 { __hip_bfloat16 h[8]; short8 s; };

// ---------------------------------------------------------------------------
// adaln: mod[b,e] = dot(silu(diff_ts[b,:]), adaln_w[e,:]) + adaln_b[e]
// grid 32 = 4 batches x 8 chunks of 256 outputs
__global__ void __launch_bounds__(256) k_adaln_mod(const float* __restrict__ dts,
                                                   const float* __restrict__ w,
                                                   const float* __restrict__ b,
                                                   float* __restrict__ mod) {
    __shared__ float sd[1024];
    int bb = blockIdx.x >> 3;
    int e  = ((blockIdx.x & 7) << 8) + threadIdx.x;
    for (int i = threadIdx.x; i < 1024; i += 256) {
        float x = dts[bb * 1024 + i];
        sd[i] = x / (1.f + __expf(-x));
    }
    __syncthreads();
    const float* wr = w + (size_t)e * 1024;
    float acc = 0.f;
    for (int k = 0; k < 1024; k += 4) {
        float4 wv = *(const float4*)(wr + k);
        acc += wv.x * sd[k] + wv.y * sd[k + 1] + wv.z * sd[k + 2] + wv.w * sd[k + 3];
    }
    mod[bb * 2048 + e] = acc + b[e];
}

// aq = query*(1+scale)+shift  -> bf16
__global__ void __launch_bounds__(256) k_modulate(const float* __restrict__ q,
                                                  const float* __restrict__ mod,
                                                  __hip_bfloat16* __restrict__ aq) {
    int idx = blockIdx.x * 256 + threadIdx.x;   // 4096*256 total
    int m = idx >> 8, o = (idx & 255) << 2;
    int bb = m >> 10;
    float4 qv = *(const float4*)(q + (size_t)m * 1024 + o);
    float4 sc = *(const float4*)(mod + bb * 2048 + o);
    float4 sh = *(const float4*)(mod + bb * 2048 + 1024 + o);
    B4 t;
    t.h[0] = __float2bfloat16(qv.x * (1.f + sc.x) + sh.x);
    t.h[1] = __float2bfloat16(qv.y * (1.f + sc.y) + sh.y);
    t.h[2] = __float2bfloat16(qv.z * (1.f + sc.z) + sh.z);
    t.h[3] = __float2bfloat16(qv.w * (1.f + sc.w) + sh.w);
    *(uint2*)(aq + (size_t)m * 1024 + o) = t.v;
}

// generic f32 -> bf16 cast (n4 = n/4)
__global__ void __launch_bounds__(256) k_cast(const float* __restrict__ in,
                                              __hip_bfloat16* __restrict__ out, int n4) {
    int i = blockIdx.x * 256 + threadIdx.x;
    if (i >= n4) return;
    float4 v = ((const float4*)in)[i];
    B4 t;
    t.h[0] = __float2bfloat16(v.x); t.h[1] = __float2bfloat16(v.y);
    t.h[2] = __float2bfloat16(v.z); t.h[3] = __float2bfloat16(v.w);
    ((uint2*)out)[i] = t.v;
}

// w_xproj (96,2048) -> bf16 padded to (128,2048), rows 96..127 = 0
__global__ void __launch_bounds__(256) k_cast_pad_xproj(const float* __restrict__ in,
                                                        __hip_bfloat16* __restrict__ out) {
    int i = blockIdx.x * 256 + threadIdx.x;     // 65536 total
    int e = i >> 9, o = (i & 511) << 2;
    float4 v = make_float4(0.f, 0.f, 0.f, 0.f);
    if (e < 96) v = *(const float4*)&in[e * 2048 + o];
    B4 t;
    t.h[0] = __float2bfloat16(v.x); t.h[1] = __float2bfloat16(v.y);
    t.h[2] = __float2bfloat16(v.z); t.h[3] = __float2bfloat16(v.w);
    *(uint2*)&out[e * 2048 + o] = t.v;
}

// dt slice of x_dbl (ld 128, cols 0..63) -> bf16 (4096 x 64)
__global__ void __launch_bounds__(256) k_cast_dt(const float* __restrict__ x_dbl,
                                                 __hip_bfloat16* __restrict__ dt) {
    int i = blockIdx.x * 256 + threadIdx.x;     // 65536 total
    int m = i >> 4, o = (i & 15) << 2;
    float4 v = *(const float4*)&x_dbl[m * 128 + o];
    B4 t;
    t.h[0] = __float2bfloat16(v.x); t.h[1] = __float2bfloat16(v.y);
    t.h[2] = __float2bfloat16(v.z); t.h[3] = __float2bfloat16(v.w);
    *(uint2*)&dt[m * 64 + o] = t.v;
}

// ---------------------------------------------------------------------------
// NT GEMM: C[M,N] = A[M,K] * B[N,K]^T, bf16 in, f32 acc. 128x128 tile, BK=32,
// 4 waves (2x2 of 64x64), mfma_f32_16x16x32_bf16.
// EPI: 0 store bf16; 1 store f32; 2 softplus(x+ep[col]) f32; 3 x+ep[row*ldc+col] f32
template <int EPI>
__global__ void __launch_bounds__(256) k_gemm_nt(const __hip_bfloat16* __restrict__ A, int lda,
                                                 const __hip_bfloat16* __restrict__ B, int ldb,
                                                 float* __restrict__ Cf,
                                                 __hip_bfloat16* __restrict__ Cb, int ldc,
                                                 int K, const float* __restrict__ ep) {
    __shared__ short As[128 * 40];   // row stride 40 shorts = 80B (breaks pow2 bank stride)
    __shared__ short Bs[128 * 40];
    int tid = threadIdx.x;
    int lane = tid & 63, wid = tid >> 6;
    int row0 = blockIdx.y << 7, col0 = blockIdx.x << 7;
    int wm = (wid >> 1) << 6, wn = (wid & 1) << 6;
    int fr = lane & 15, ko = (lane >> 4) << 3;

    int ra0 = tid >> 2, oa = (tid & 3) << 3;   // piece tid: rows 0..63
    int ra1 = ra0 + 64;                         // piece tid+256: rows 64..127

    const short* Ag = (const short*)A;
    const short* Bg = (const short*)B;

    f32x4 acc[4][4] = {};

    for (int k0 = 0; k0 < K; k0 += 32) {
        __syncthreads();
        *(short8*)&As[ra0 * 40 + oa] = *(const short8*)&Ag[(size_t)(row0 + ra0) * lda + k0 + oa];
        *(short8*)&As[ra1 * 40 + oa] = *(const short8*)&Ag[(size_t)(row0 + ra1) * lda + k0 + oa];
        *(short8*)&Bs[ra0 * 40 + oa] = *(const short8*)&Bg[(size_t)(col0 + ra0) * ldb + k0 + oa];
        *(short8*)&Bs[ra1 * 40 + oa] = *(const short8*)&Bg[(size_t)(col0 + ra1) * ldb + k0 + oa];
        __syncthreads();
        short8 a[4], b[4];
#pragma unroll
        for (int mi = 0; mi < 4; ++mi) a[mi] = *(const short8*)&As[(wm + mi * 16 + fr) * 40 + ko];
#pragma unroll
        for (int ni = 0; ni < 4; ++ni) b[ni] = *(const short8*)&Bs[(wn + ni * 16 + fr) * 40 + ko];
#pragma unroll
        for (int mi = 0; mi < 4; ++mi)
#pragma unroll
            for (int ni = 0; ni < 4; ++ni)
                acc[mi][ni] = __builtin_amdgcn_mfma_f32_16x16x32_bf16(a[mi], b[ni], acc[mi][ni], 0, 0, 0);
    }

    int er = (lane >> 4) << 2;   // C/D: col = lane&15, row = (lane>>4)*4 + r  [m89]
    int ec = lane & 15;
#pragma unroll
    for (int mi = 0; mi < 4; ++mi)
#pragma unroll
        for (int ni = 0; ni < 4; ++ni)
#pragma unroll
            for (int r = 0; r < 4; ++r) {
                int gr = row0 + wm + mi * 16 + er + r;
                int gc = col0 + wn + ni * 16 + ec;
                size_t off = (size_t)gr * ldc + gc;
                float v = acc[mi][ni][r];
                if (EPI == 0) {
                    Cb[off] = __float2bfloat16(v);
                } else if (EPI == 1) {
                    Cf[off] = v;
                } else if (EPI == 2) {
                    float x = v + ep[gc];
                    Cf[off] = (x > 20.f) ? x : log1pf(__expf(x));
                } else {
                    Cf[off] = v + ep[off];
                }
            }
}

// ---------------------------------------------------------------------------
// causal depthwise conv (window 4) + bias + silu:  u_act = silu(conv(xz[:, :2048]))
__global__ void __launch_bounds__(256) k_conv(const __hip_bfloat16* __restrict__ xz,
                                              const float* __restrict__ cw,
                                              const float* __restrict__ cb,
                                              __hip_bfloat16* __restrict__ u_act) {
    int idx = blockIdx.x * 256 + threadIdx.x;   // 4096*256
    int m = idx >> 8, d = (idx & 255) << 3;
    int l = m & 1023;
    float acc[8];
#pragma unroll
    for (int j = 0; j < 8; ++j) acc[j] = cb[d + j];
#pragma unroll
    for (int k = 0; k < 4; ++k) {
        int lt = l - 3 + k;
        if (lt < 0) continue;
        B8 v;
        v.s = *(const short8*)(xz + (size_t)(m - 3 + k) * 4096 + d);
#pragma unroll
        for (int j = 0; j < 8; ++j)
            acc[j] += __bfloat162float(v.h[j]) * cw[(d + j) * 4 + k];
    }
    B8 o;
#pragma unroll
    for (int j = 0; j < 8; ++j) {
        float x = acc[j];
        o.h[j] = __float2bfloat16(x / (1.f + __expf(-x)));
    }
    *(short8*)(u_act + (size_t)m * 2048 + d) = o.s;
}

// ---------------------------------------------------------------------------
// selective scan. Block = 256 thr = 4 waves; block owns (b, 16 d-channels).
// lane: s = lane&15 (state), dl = wid*4 + (lane>>4) (local channel).
// Chunks of 64 timesteps staged in LDS. Fused epilogue: +u*d_skip, *silu(z).
__global__ void __launch_bounds__(256) k_scan(const float* __restrict__ delta,
                                              const __hip_bfloat16* __restrict__ u_act,
                                              const __hip_bfloat16* __restrict__ xz,
                                              const float* __restrict__ x_dbl,
                                              const float* __restrict__ a_log,
                                              const float* __restrict__ d_skip,
                                              __hip_bfloat16* __restrict__ y) {
    __shared__ __align__(16) float sDelta[64][16];
    __shared__ __align__(16) float sB[64][16];
    __shared__ __align__(16) float sC[64][16];
    __shared__ __align__(16) __hip_bfloat16 sU[64][16];
    __shared__ __align__(16) __hip_bfloat16 sZ[64][16];
    __shared__ __align__(16) __hip_bfloat16 sY[64][16];

    int tid = threadIdx.x;
    int lane = tid & 63, wid = tid >> 6;
    int s = lane & 15, dl = (wid << 2) + (lane >> 4);
    int bb = blockIdx.x >> 7;
    int d_base = (blockIdx.x & 127) << 4;
    int d = d_base + dl;
    float Aval = -__expf(a_log[d * 16 + s]);
    float dsk = d_skip[d];
    float h = 0.f;
    int r = tid >> 2, o4 = (tid & 3) << 2;
    int row0 = bb << 10;

    for (int c = 0; c < 16; ++c) {
        int m = row0 + (c << 6) + r;
        __syncthreads();
        *(float4*)&sDelta[r][o4] = *(const float4*)&delta[(size_t)m * 2048 + d_base + o4];
        *(float4*)&sB[r][o4]     = *(const float4*)&x_dbl[m * 128 + 64 + o4];
        *(float4*)&sC[r][o4]     = *(const float4*)&x_dbl[m * 128 + 80 + o4];
        *(uint2*)&sU[r][o4]      = *(const uint2*)&u_act[(size_t)m * 2048 + d_base + o4];
        *(uint2*)&sZ[r][o4]      = *(const uint2*)&xz[(size_t)m * 4096 + 2048 + d_base + o4];
        __syncthreads();
#pragma unroll 4
        for (int t = 0; t < 64; ++t) {
            float dt = sDelta[t][dl];
            float uv = __bfloat162float(sU[t][dl]);
            float dA = __expf(dt * Aval);
            h = fmaf(dA, h, dt * uv * sB[t][s]);
            float p = h * sC[t][s];
            p += __shfl_xor(p, 1, 16);
            p += __shfl_xor(p, 2, 16);
            p += __shfl_xor(p, 4, 16);
            p += __shfl_xor(p, 8, 16);
            if (s == 0) {
                float zv = __bfloat162float(sZ[t][dl]);
                float yv = (p + uv * dsk) * (zv / (1.f + __expf(-zv)));
                sY[t][dl] = __float2bfloat16(yv);
            }
        }
        __syncthreads();
        *(uint2*)&y[(size_t)m * 2048 + d_base + o4] = *(uint2*)&sY[r][o4];
    }
}

// ---------------------------------------------------------------------------
// layernorm in-place on d_out rows of 1024
__global__ void __launch_bounds__(256) k_ln(float* __restrict__ out,
                                            const float* __restrict__ g,
                                            const float* __restrict__ b) {
    int row = blockIdx.x;
    float* p = out + (size_t)row * 1024;
    int tid = threadIdx.x;
    float4 v = ((float4*)p)[tid];
    float s1 = v.x + v.y + v.z + v.w;
    float s2 = v.x * v.x + v.y * v.y + v.z * v.z + v.w * v.w;
    for (int off = 1; off < 64; off <<= 1) {
        s1 += __shfl_xor(s1, off, 64);
        s2 += __shfl_xor(s2, off, 64);
    }
    __shared__ float a1[4], a2[4];
    int wid = tid >> 6;
    if ((tid & 63) == 0) { a1[wid] = s1; a2[wid] = s2; }
    __syncthreads();
    s1 = a1[0] + a1[1] + a1[2] + a1[3];
    s2 = a2[0] + a2[1] + a2[2] + a2[3];
    float mean = s1 * (1.f / 1024.f);
    float var = s2 * (1.f / 1024.f) - mean * mean;
    float inv = rsqrtf(var + 1e-5f);
    float4 gv = ((const float4*)g)[tid];
    float4 bv = ((const float4*)b)[tid];
    v.x = (v.x - mean) * inv * gv.x + bv.x;
    v.y = (v.y - mean) * inv * gv.y + bv.y;
    v.z = (v.z - mean) * inv * gv.z + bv.z;
    v.w = (v.w - mean) * inv * gv.w + bv.w;
    ((float4*)p)[tid] = v;
}

// ---------------------------------------------------------------------------
extern "C" void kernel_launch(void* const* d_in, const int* in_sizes, int n_in,
                              void* d_out, int out_size, void* d_ws, size_t ws_size,
                              hipStream_t stream) {
    const float* query   = (const float*)d_in[0];
    const float* diff_ts = (const float*)d_in[1];
    const float* adaln_w = (const float*)d_in[2];
    const float* adaln_b = (const float*)d_in[3];
    const float* w_in    = (const float*)d_in[4];
    const float* conv_w  = (const float*)d_in[5];
    const float* conv_b  = (const float*)d_in[6];
    const float* w_xproj = (const float*)d_in[7];
    const float* w_dt    = (const float*)d_in[8];
    const float* b_dt    = (const float*)d_in[9];
    const float* a_log   = (const float*)d_in[10];
    const float* d_skip  = (const float*)d_in[11];
    const float* w_out   = (const float*)d_in[12];
    const float* ln_g    = (const float*)d_in[13];
    const float* ln_b    = (const float*)d_in[14];
    float* out = (float*)d_out;

    char* w = (char*)d_ws;
    auto alloc = [&](size_t bytes) -> char* {
        char* p = w;
        w += (bytes + 255) & ~(size_t)255;
        return p;
    };
    float*          mod     = (float*)         alloc((size_t)4 * 2048 * 4);
    __hip_bfloat16* aq      = (__hip_bfloat16*)alloc((size_t)4096 * 1024 * 2);
    __hip_bfloat16* w_in_b  = (__hip_bfloat16*)alloc((size_t)4096 * 1024 * 2);
    __hip_bfloat16* w_out_b = (__hip_bfloat16*)alloc((size_t)1024 * 2048 * 2);
    __hip_bfloat16* w_xp_b  = (__hip_bfloat16*)alloc((size_t)128 * 2048 * 2);
    __hip_bfloat16* w_dt_b  = (__hip_bfloat16*)alloc((size_t)2048 * 64 * 2);
    __hip_bfloat16* xz      = (__hip_bfloat16*)alloc((size_t)4096 * 4096 * 2);
    __hip_bfloat16* u_act   = (__hip_bfloat16*)alloc((size_t)4096 * 2048 * 2);
    float*          x_dbl   = (float*)         alloc((size_t)4096 * 128 * 4);
    __hip_bfloat16* dtb     = (__hip_bfloat16*)alloc((size_t)4096 * 64 * 2);
    float*          delta   = (float*)         alloc((size_t)4096 * 2048 * 4);
    __hip_bfloat16* yb      = (__hip_bfloat16*)alloc((size_t)4096 * 2048 * 2);

    k_adaln_mod<<<32, 256, 0, stream>>>(diff_ts, adaln_w, adaln_b, mod);
    k_modulate<<<4096, 256, 0, stream>>>(query, mod, aq);
    k_cast<<<4096, 256, 0, stream>>>(w_in, w_in_b, 4096 * 1024 / 4);
    k_cast<<<2048, 256, 0, stream>>>(w_out, w_out_b, 1024 * 2048 / 4);
    k_cast_pad_xproj<<<256, 256, 0, stream>>>(w_xproj, w_xp_b);
    k_cast<<<128, 256, 0, stream>>>(w_dt, w_dt_b, 2048 * 64 / 4);

    // xz = aq @ w_in^T   (M=4096, N=4096, K=1024) -> bf16
    k_gemm_nt<0><<<dim3(32, 32), 256, 0, stream>>>(aq, 1024, w_in_b, 1024,
                                                   nullptr, xz, 4096, 1024, nullptr);
    // conv + silu -> u_act
    k_conv<<<4096, 256, 0, stream>>>(xz, conv_w, conv_b, u_act);
    // x_dbl = u_act @ w_xprojP^T (M=4096, N=128(pad), K=2048) -> f32 ld 128
    k_gemm_nt<1><<<dim3(1, 32), 256, 0, stream>>>(u_act, 2048, w_xp_b, 2048,
                                                  x_dbl, nullptr, 128, 2048, nullptr);
    k_cast_dt<<<256, 256, 0, stream>>>(x_dbl, dtb);
    // delta = softplus(dt @ w_dt^T + b_dt) (M=4096, N=2048, K=64) -> f32
    k_gemm_nt<2><<<dim3(16, 32), 256, 0, stream>>>(dtb, 64, w_dt_b, 64,
                                                   delta, nullptr, 2048, 64, b_dt);
    // selective scan -> yb (fused +u*d_skip, *silu(z))
    k_scan<<<512, 256, 0, stream>>>(delta, u_act, xz, x_dbl, a_log, d_skip, yb);
    // out_pre = yb @ w_out^T + query (M=4096, N=1024, K=2048) -> f32 d_out
    k_gemm_nt<3><<<dim3(8, 32), 256, 0, stream>>>(yb, 2048, w_out_b, 2048,
                                                  out, nullptr, 1024, 2048, query);
    // layernorm in place
    k_ln<<<4096, 256, 0, stream>>>(out, ln_g, ln_b);
}

// Round 10
// 532.745 us; speedup vs baseline: 1.2660x; 1.2660x over previous
//
#include <hip/hip_runtime.h>
#include <hip/hip_bf16.h>

typedef __attribute__((ext_vector_type(8))) short short8;
typedef __attribute__((ext_vector_type(4))) float f32x4;

union B4 { __hip_bfloat16 h[4]; uint2 v; };
union B8 { __hip_bfloat16 h[8]; short8 s; };

// ---------------------------------------------------------------------------
// adaln: mod[b,e] = dot(silu(diff_ts[b,:]), adaln_w[e,:]) + adaln_b[e]
__global__ void __launch_bounds__(256) k_adaln_mod(const float* __restrict__ dts,
                                                   const float* __restrict__ w,
                                                   const float* __restrict__ b,
                                                   float* __restrict__ mod) {
    __shared__ float sd[1024];
    int bb = blockIdx.x >> 3;
    int e  = ((blockIdx.x & 7) << 8) + threadIdx.x;
    for (int i = threadIdx.x; i < 1024; i += 256) {
        float x = dts[bb * 1024 + i];
        sd[i] = x / (1.f + __expf(-x));
    }
    __syncthreads();
    const float* wr = w + (size_t)e * 1024;
    float acc = 0.f;
    for (int k = 0; k < 1024; k += 4) {
        float4 wv = *(const float4*)(wr + k);
        acc += wv.x * sd[k] + wv.y * sd[k + 1] + wv.z * sd[k + 2] + wv.w * sd[k + 3];
    }
    mod[bb * 2048 + e] = acc + b[e];
}

// aq = query*(1+scale)+shift  -> bf16
__global__ void __launch_bounds__(256) k_modulate(const float* __restrict__ q,
                                                  const float* __restrict__ mod,
                                                  __hip_bfloat16* __restrict__ aq) {
    int idx = blockIdx.x * 256 + threadIdx.x;   // 4096*256 total
    int m = idx >> 8, o = (idx & 255) << 2;
    int bb = m >> 10;
    float4 qv = *(const float4*)(q + (size_t)m * 1024 + o);
    float4 sc = *(const float4*)(mod + bb * 2048 + o);
    float4 sh = *(const float4*)(mod + bb * 2048 + 1024 + o);
    B4 t;
    t.h[0] = __float2bfloat16(qv.x * (1.f + sc.x) + sh.x);
    t.h[1] = __float2bfloat16(qv.y * (1.f + sc.y) + sh.y);
    t.h[2] = __float2bfloat16(qv.z * (1.f + sc.z) + sh.z);
    t.h[3] = __float2bfloat16(qv.w * (1.f + sc.w) + sh.w);
    *(uint2*)(aq + (size_t)m * 1024 + o) = t.v;
}

// generic f32 -> bf16 cast (n4 = n/4)
__global__ void __launch_bounds__(256) k_cast(const float* __restrict__ in,
                                              __hip_bfloat16* __restrict__ out, int n4) {
    int i = blockIdx.x * 256 + threadIdx.x;
    if (i >= n4) return;
    float4 v = ((const float4*)in)[i];
    B4 t;
    t.h[0] = __float2bfloat16(v.x); t.h[1] = __float2bfloat16(v.y);
    t.h[2] = __float2bfloat16(v.z); t.h[3] = __float2bfloat16(v.w);
    ((uint2*)out)[i] = t.v;
}

// w_xproj (96,2048) -> bf16 padded to (128,2048), rows 96..127 = 0
__global__ void __launch_bounds__(256) k_cast_pad_xproj(const float* __restrict__ in,
                                                        __hip_bfloat16* __restrict__ out) {
    int i = blockIdx.x * 256 + threadIdx.x;     // 65536 total
    int e = i >> 9, o = (i & 511) << 2;
    float4 v = make_float4(0.f, 0.f, 0.f, 0.f);
    if (e < 96) v = *(const float4*)&in[e * 2048 + o];
    B4 t;
    t.h[0] = __float2bfloat16(v.x); t.h[1] = __float2bfloat16(v.y);
    t.h[2] = __float2bfloat16(v.z); t.h[3] = __float2bfloat16(v.w);
    *(uint2*)&out[e * 2048 + o] = t.v;
}

// dt slice of x_dbl (ld 128, cols 0..63) -> bf16 (4096 x 64)
__global__ void __launch_bounds__(256) k_cast_dt(const float* __restrict__ x_dbl,
                                                 __hip_bfloat16* __restrict__ dt) {
    int i = blockIdx.x * 256 + threadIdx.x;     // 65536 total
    int m = i >> 4, o = (i & 15) << 2;
    float4 v = *(const float4*)&x_dbl[m * 128 + o];
    B4 t;
    t.h[0] = __float2bfloat16(v.x); t.h[1] = __float2bfloat16(v.y);
    t.h[2] = __float2bfloat16(v.z); t.h[3] = __float2bfloat16(v.w);
    *(uint2*)&dt[m * 64 + o] = t.v;
}

// ---------------------------------------------------------------------------
// NT GEMM: C[M,N] = A[M,K] * B[N,K]^T, bf16 in, f32 acc. 128x128 tile, BK=32,
// 4 waves (2x2 of 64x64), mfma_f32_16x16x32_bf16.
// EPI: 0 store bf16; 1 store f32; 2 softplus(x+ep[col]) f32; 3 x+ep[row*ldc+col] f32
template <int EPI>
__global__ void __launch_bounds__(256) k_gemm_nt(const __hip_bfloat16* __restrict__ A, int lda,
                                                 const __hip_bfloat16* __restrict__ B, int ldb,
                                                 float* __restrict__ Cf,
                                                 __hip_bfloat16* __restrict__ Cb, int ldc,
                                                 int K, const float* __restrict__ ep) {
    __shared__ short As[128 * 40];   // row stride 40 shorts = 80B (breaks pow2 bank stride)
    __shared__ short Bs[128 * 40];
    int tid = threadIdx.x;
    int lane = tid & 63, wid = tid >> 6;
    int row0 = blockIdx.y << 7, col0 = blockIdx.x << 7;
    int wm = (wid >> 1) << 6, wn = (wid & 1) << 6;
    int fr = lane & 15, ko = (lane >> 4) << 3;

    int ra0 = tid >> 2, oa = (tid & 3) << 3;   // piece tid: rows 0..63
    int ra1 = ra0 + 64;                         // piece tid+256: rows 64..127

    const short* Ag = (const short*)A;
    const short* Bg = (const short*)B;

    f32x4 acc[4][4] = {};

    for (int k0 = 0; k0 < K; k0 += 32) {
        __syncthreads();
        *(short8*)&As[ra0 * 40 + oa] = *(const short8*)&Ag[(size_t)(row0 + ra0) * lda + k0 + oa];
        *(short8*)&As[ra1 * 40 + oa] = *(const short8*)&Ag[(size_t)(row0 + ra1) * lda + k0 + oa];
        *(short8*)&Bs[ra0 * 40 + oa] = *(const short8*)&Bg[(size_t)(col0 + ra0) * ldb + k0 + oa];
        *(short8*)&Bs[ra1 * 40 + oa] = *(const short8*)&Bg[(size_t)(col0 + ra1) * ldb + k0 + oa];
        __syncthreads();
        short8 a[4], b[4];
#pragma unroll
        for (int mi = 0; mi < 4; ++mi) a[mi] = *(const short8*)&As[(wm + mi * 16 + fr) * 40 + ko];
#pragma unroll
        for (int ni = 0; ni < 4; ++ni) b[ni] = *(const short8*)&Bs[(wn + ni * 16 + fr) * 40 + ko];
#pragma unroll
        for (int mi = 0; mi < 4; ++mi)
#pragma unroll
            for (int ni = 0; ni < 4; ++ni)
                acc[mi][ni] = __builtin_amdgcn_mfma_f32_16x16x32_bf16(a[mi], b[ni], acc[mi][ni], 0, 0, 0);
    }

    int er = (lane >> 4) << 2;   // C/D: col = lane&15, row = (lane>>4)*4 + r  [m89]
    int ec = lane & 15;
#pragma unroll
    for (int mi = 0; mi < 4; ++mi)
#pragma unroll
        for (int ni = 0; ni < 4; ++ni)
#pragma unroll
            for (int r = 0; r < 4; ++r) {
                int gr = row0 + wm + mi * 16 + er + r;
                int gc = col0 + wn + ni * 16 + ec;
                size_t off = (size_t)gr * ldc + gc;
                float v = acc[mi][ni][r];
                if (EPI == 0) {
                    Cb[off] = __float2bfloat16(v);
                } else if (EPI == 1) {
                    Cf[off] = v;
                } else if (EPI == 2) {
                    float x = v + ep[gc];
                    Cf[off] = (x > 20.f) ? x : log1pf(__expf(x));
                } else {
                    Cf[off] = v + ep[off];
                }
            }
}

// ---------------------------------------------------------------------------
// causal depthwise conv (window 4) + bias + silu:  u_act = silu(conv(xz[:, :2048]))
__global__ void __launch_bounds__(256) k_conv(const __hip_bfloat16* __restrict__ xz,
                                              const float* __restrict__ cw,
                                              const float* __restrict__ cb,
                                              __hip_bfloat16* __restrict__ u_act) {
    int idx = blockIdx.x * 256 + threadIdx.x;   // 4096*256
    int m = idx >> 8, d = (idx & 255) << 3;
    int l = m & 1023;
    float acc[8];
#pragma unroll
    for (int j = 0; j < 8; ++j) acc[j] = cb[d + j];
#pragma unroll
    for (int k = 0; k < 4; ++k) {
        int lt = l - 3 + k;
        if (lt < 0) continue;
        B8 v;
        v.s = *(const short8*)(xz + (size_t)(m - 3 + k) * 4096 + d);
#pragma unroll
        for (int j = 0; j < 8; ++j)
            acc[j] += __bfloat162float(v.h[j]) * cw[(d + j) * 4 + k];
    }
    B8 o;
#pragma unroll
    for (int j = 0; j < 8; ++j) {
        float x = acc[j];
        o.h[j] = __float2bfloat16(x / (1.f + __expf(-x)));
    }
    *(short8*)(u_act + (size_t)m * 2048 + d) = o.s;
}

// ---------------------------------------------------------------------------
// Chunked parallel selective scan.  h_t = exp(dt*A)*h_{t-1} + dt*u*B_t.
// 16 chunks of 64 timesteps.  One thread owns one (b,d) channel's 16 states
// in registers; B_t/C_t are block-uniform (scalar-load path).
// Phase 1: per-chunk summaries  P = prod(dA),  S = h starting from 0.
// Phase 2: serial compose over chunks -> chS[c] overwritten with h_init[c].
// Phase 3: replay each chunk from h_init, emit y with fused epilogue.
// Summary layout: [b][c][s][d]  ->  ((b*16+c)*16+s)*2048 + d
__global__ void __launch_bounds__(256) k_scan_p1(const float* __restrict__ delta,
                                                 const __hip_bfloat16* __restrict__ u_act,
                                                 const float* __restrict__ x_dbl,
                                                 const float* __restrict__ a_log,
                                                 float* __restrict__ chP,
                                                 float* __restrict__ chS) {
    int tid = threadIdx.x;
    int bid = blockIdx.x;            // 512 = 4b x 16c x 8dg
    int bb = bid >> 7;
    int c  = (bid >> 3) & 15;
    int dg = bid & 7;
    int d  = (dg << 8) + tid;
    float A2[16], P[16], h[16];
#pragma unroll
    for (int s = 0; s < 16; ++s) {
        A2[s] = -__expf(a_log[d * 16 + s]) * 1.44269504f;   // pre-fold log2(e)
        P[s] = 1.f;
        h[s] = 0.f;
    }
    int m0 = (bb << 10) + (c << 6);
    for (int t = 0; t < 64; ++t) {
        int m = m0 + t;
        float dt = delta[(size_t)m * 2048 + d];
        float uv = __bfloat162float(u_act[(size_t)m * 2048 + d]);
        float x = dt * uv;
        const float* Brow = x_dbl + (size_t)m * 128 + 64;   // uniform across block
#pragma unroll
        for (int s = 0; s < 16; ++s) {
            float dA = exp2f(dt * A2[s]);
            P[s] *= dA;
            h[s] = fmaf(dA, h[s], x * Brow[s]);
        }
    }
    size_t base = (size_t)((bb * 16 + c) * 16) * 2048 + d;
#pragma unroll
    for (int s = 0; s < 16; ++s) {
        chP[base + (size_t)s * 2048] = P[s];
        chS[base + (size_t)s * 2048] = h[s];
    }
}

// one thread per (b,d,s): 16-step serial compose; chS becomes h_init per chunk
__global__ void __launch_bounds__(256) k_scan_p2(const float* __restrict__ chP,
                                                 float* __restrict__ chS) {
    int idx = blockIdx.x * 256 + threadIdx.x;   // 131072 = 4b x 16s x 2048d
    int bb = idx >> 15;
    int s  = (idx >> 11) & 15;
    int d  = idx & 2047;
    float h = 0.f;
    for (int c = 0; c < 16; ++c) {
        size_t off = (size_t)((bb * 16 + c) * 16 + s) * 2048 + d;
        float Pv = chP[off];
        float Sv = chS[off];
        chS[off] = h;                 // h_init for chunk c (state before chunk c)
        h = fmaf(Pv, h, Sv);
    }
}

__global__ void __launch_bounds__(256) k_scan_p3(const float* __restrict__ delta,
                                                 const __hip_bfloat16* __restrict__ u_act,
                                                 const __hip_bfloat16* __restrict__ xz,
                                                 const float* __restrict__ x_dbl,
                                                 const float* __restrict__ a_log,
                                                 const float* __restrict__ d_skip,
                                                 const float* __restrict__ hinit,
                                                 __hip_bfloat16* __restrict__ y) {
    int tid = threadIdx.x;
    int bid = blockIdx.x;            // 512 = 4b x 16c x 8dg
    int bb = bid >> 7;
    int c  = (bid >> 3) & 15;
    int dg = bid & 7;
    int d  = (dg << 8) + tid;
    float A2[16], h[16];
    size_t base = (size_t)((bb * 16 + c) * 16) * 2048 + d;
#pragma unroll
    for (int s = 0; s < 16; ++s) {
        A2[s] = -__expf(a_log[d * 16 + s]) * 1.44269504f;
        h[s] = hinit[base + (size_t)s * 2048];
    }
    float dsk = d_skip[d];
    int m0 = (bb << 10) + (c << 6);
    for (int t = 0; t < 64; ++t) {
        int m = m0 + t;
        float dt = delta[(size_t)m * 2048 + d];
        float uv = __bfloat162float(u_act[(size_t)m * 2048 + d]);
        float x = dt * uv;
        const float* Brow = x_dbl + (size_t)m * 128 + 64;
        const float* Crow = Brow + 16;
        float yacc = 0.f;
#pragma unroll
        for (int s = 0; s < 16; ++s) {
            float dA = exp2f(dt * A2[s]);
            h[s] = fmaf(dA, h[s], x * Brow[s]);
            yacc = fmaf(h[s], Crow[s], yacc);
        }
        float zv = __bfloat162float(xz[(size_t)m * 4096 + 2048 + d]);
        float yv = (yacc + uv * dsk) * (zv / (1.f + __expf(-zv)));
        y[(size_t)m * 2048 + d] = __float2bfloat16(yv);
    }
}

// ---------------------------------------------------------------------------
// layernorm in-place on d_out rows of 1024
__global__ void __launch_bounds__(256) k_ln(float* __restrict__ out,
                                            const float* __restrict__ g,
                                            const float* __restrict__ b) {
    int row = blockIdx.x;
    float* p = out + (size_t)row * 1024;
    int tid = threadIdx.x;
    float4 v = ((float4*)p)[tid];
    float s1 = v.x + v.y + v.z + v.w;
    float s2 = v.x * v.x + v.y * v.y + v.z * v.z + v.w * v.w;
    for (int off = 1; off < 64; off <<= 1) {
        s1 += __shfl_xor(s1, off, 64);
        s2 += __shfl_xor(s2, off, 64);
    }
    __shared__ float a1[4], a2[4];
    int wid = tid >> 6;
    if ((tid & 63) == 0) { a1[wid] = s1; a2[wid] = s2; }
    __syncthreads();
    s1 = a1[0] + a1[1] + a1[2] + a1[3];
    s2 = a2[0] + a2[1] + a2[2] + a2[3];
    float mean = s1 * (1.f / 1024.f);
    float var = s2 * (1.f / 1024.f) - mean * mean;
    float inv = rsqrtf(var + 1e-5f);
    float4 gv = ((const float4*)g)[tid];
    float4 bv = ((const float4*)b)[tid];
    v.x = (v.x - mean) * inv * gv.x + bv.x;
    v.y = (v.y - mean) * inv * gv.y + bv.y;
    v.z = (v.z - mean) * inv * gv.z + bv.z;
    v.w = (v.w - mean) * inv * gv.w + bv.w;
    ((float4*)p)[tid] = v;
}

// ---------------------------------------------------------------------------
extern "C" void kernel_launch(void* const* d_in, const int* in_sizes, int n_in,
                              void* d_out, int out_size, void* d_ws, size_t ws_size,
                              hipStream_t stream) {
    const float* query   = (const float*)d_in[0];
    const float* diff_ts = (const float*)d_in[1];
    const float* adaln_w = (const float*)d_in[2];
    const float* adaln_b = (const float*)d_in[3];
    const float* w_in    = (const float*)d_in[4];
    const float* conv_w  = (const float*)d_in[5];
    const float* conv_b  = (const float*)d_in[6];
    const float* w_xproj = (const float*)d_in[7];
    const float* w_dt    = (const float*)d_in[8];
    const float* b_dt    = (const float*)d_in[9];
    const float* a_log   = (const float*)d_in[10];
    const float* d_skip  = (const float*)d_in[11];
    const float* w_out   = (const float*)d_in[12];
    const float* ln_g    = (const float*)d_in[13];
    const float* ln_b    = (const float*)d_in[14];
    float* out = (float*)d_out;

    char* w = (char*)d_ws;
    auto alloc = [&](size_t bytes) -> char* {
        char* p = w;
        w += (bytes + 255) & ~(size_t)255;
        return p;
    };
    float*          mod     = (float*)         alloc((size_t)4 * 2048 * 4);
    __hip_bfloat16* aq      = (__hip_bfloat16*)alloc((size_t)4096 * 1024 * 2);
    __hip_bfloat16* w_in_b  = (__hip_bfloat16*)alloc((size_t)4096 * 1024 * 2);
    __hip_bfloat16* w_out_b = (__hip_bfloat16*)alloc((size_t)1024 * 2048 * 2);
    __hip_bfloat16* w_xp_b  = (__hip_bfloat16*)alloc((size_t)128 * 2048 * 2);
    __hip_bfloat16* w_dt_b  = (__hip_bfloat16*)alloc((size_t)2048 * 64 * 2);
    __hip_bfloat16* xz      = (__hip_bfloat16*)alloc((size_t)4096 * 4096 * 2);
    __hip_bfloat16* u_act   = (__hip_bfloat16*)alloc((size_t)4096 * 2048 * 2);
    float*          x_dbl   = (float*)         alloc((size_t)4096 * 128 * 4);
    __hip_bfloat16* dtb     = (__hip_bfloat16*)alloc((size_t)4096 * 64 * 2);
    float*          delta   = (float*)         alloc((size_t)4096 * 2048 * 4);
    __hip_bfloat16* yb      = (__hip_bfloat16*)alloc((size_t)4096 * 2048 * 2);
    float*          chP     = (float*)         alloc((size_t)4 * 16 * 16 * 2048 * 4);
    float*          chS     = (float*)         alloc((size_t)4 * 16 * 16 * 2048 * 4);

    k_adaln_mod<<<32, 256, 0, stream>>>(diff_ts, adaln_w, adaln_b, mod);
    k_modulate<<<4096, 256, 0, stream>>>(query, mod, aq);
    k_cast<<<4096, 256, 0, stream>>>(w_in, w_in_b, 4096 * 1024 / 4);
    k_cast<<<2048, 256, 0, stream>>>(w_out, w_out_b, 1024 * 2048 / 4);
    k_cast_pad_xproj<<<256, 256, 0, stream>>>(w_xproj, w_xp_b);
    k_cast<<<128, 256, 0, stream>>>(w_dt, w_dt_b, 2048 * 64 / 4);

    // xz = aq @ w_in^T   (M=4096, N=4096, K=1024) -> bf16
    k_gemm_nt<0><<<dim3(32, 32), 256, 0, stream>>>(aq, 1024, w_in_b, 1024,
                                                   nullptr, xz, 4096, 1024, nullptr);
    // conv + silu -> u_act
    k_conv<<<4096, 256, 0, stream>>>(xz, conv_w, conv_b, u_act);
    // x_dbl = u_act @ w_xprojP^T (M=4096, N=128(pad), K=2048) -> f32 ld 128
    k_gemm_nt<1><<<dim3(1, 32), 256, 0, stream>>>(u_act, 2048, w_xp_b, 2048,
                                                  x_dbl, nullptr, 128, 2048, nullptr);
    k_cast_dt<<<256, 256, 0, stream>>>(x_dbl, dtb);
    // delta = softplus(dt @ w_dt^T + b_dt) (M=4096, N=2048, K=64) -> f32
    k_gemm_nt<2><<<dim3(16, 32), 256, 0, stream>>>(dtb, 64, w_dt_b, 64,
                                                   delta, nullptr, 2048, 64, b_dt);
    // chunked parallel selective scan -> yb (fused +u*d_skip, *silu(z))
    k_scan_p1<<<512, 256, 0, stream>>>(delta, u_act, x_dbl, a_log, chP, chS);
    k_scan_p2<<<512, 256, 0, stream>>>(chP, chS);
    k_scan_p3<<<512, 256, 0, stream>>>(delta, u_act, xz, x_dbl, a_log, d_skip, chS, yb);
    // out_pre = yb @ w_out^T + query (M=4096, N=1024, K=2048) -> f32 d_out
    k_gemm_nt<3><<<dim3(8, 32), 256, 0, stream>>>(yb, 2048, w_out_b, 2048,
                                                  out, nullptr, 1024, 2048, query);
    // layernorm in place
    k_ln<<<4096, 256, 0, stream>>>(out, ln_g, ln_b);
}

// Round 12
// 513.709 us; speedup vs baseline: 1.3129x; 1.0371x over previous
//
#include <hip/hip_runtime.h>
#include <hip/hip_bf16.h>

typedef __attribute__((ext_vector_type(8))) short short8;
typedef __attribute__((ext_vector_type(4))) float f32x4;

union B4 { __hip_bfloat16 h[4]; uint2 v; };
union B8 { __hip_bfloat16 h[8]; short8 s; };

// ---------------------------------------------------------------------------
// adaln: mod[b,e] = dot(silu(diff_ts[b,:]), adaln_w[e,:]) + adaln_b[e]
__global__ void __launch_bounds__(256) k_adaln_mod(const float* __restrict__ dts,
                                                   const float* __restrict__ w,
                                                   const float* __restrict__ b,
                                                   float* __restrict__ mod) {
    __shared__ float sd[1024];
    int bb = blockIdx.x >> 3;
    int e  = ((blockIdx.x & 7) << 8) + threadIdx.x;
    for (int i = threadIdx.x; i < 1024; i += 256) {
        float x = dts[bb * 1024 + i];
        sd[i] = x / (1.f + __expf(-x));
    }
    __syncthreads();
    const float* wr = w + (size_t)e * 1024;
    float acc = 0.f;
    for (int k = 0; k < 1024; k += 4) {
        float4 wv = *(const float4*)(wr + k);
        acc += wv.x * sd[k] + wv.y * sd[k + 1] + wv.z * sd[k + 2] + wv.w * sd[k + 3];
    }
    mod[bb * 2048 + e] = acc + b[e];
}

// aq = query*(1+scale)+shift  -> bf16
__global__ void __launch_bounds__(256) k_modulate(const float* __restrict__ q,
                                                  const float* __restrict__ mod,
                                                  __hip_bfloat16* __restrict__ aq) {
    int idx = blockIdx.x * 256 + threadIdx.x;   // 4096*256 total
    int m = idx >> 8, o = (idx & 255) << 2;
    int bb = m >> 10;
    float4 qv = *(const float4*)(q + (size_t)m * 1024 + o);
    float4 sc = *(const float4*)(mod + bb * 2048 + o);
    float4 sh = *(const float4*)(mod + bb * 2048 + 1024 + o);
    B4 t;
    t.h[0] = __float2bfloat16(qv.x * (1.f + sc.x) + sh.x);
    t.h[1] = __float2bfloat16(qv.y * (1.f + sc.y) + sh.y);
    t.h[2] = __float2bfloat16(qv.z * (1.f + sc.z) + sh.z);
    t.h[3] = __float2bfloat16(qv.w * (1.f + sc.w) + sh.w);
    *(uint2*)(aq + (size_t)m * 1024 + o) = t.v;
}

// generic f32 -> bf16 cast (n4 = n/4)
__global__ void __launch_bounds__(256) k_cast(const float* __restrict__ in,
                                              __hip_bfloat16* __restrict__ out, int n4) {
    int i = blockIdx.x * 256 + threadIdx.x;
    if (i >= n4) return;
    float4 v = ((const float4*)in)[i];
    B4 t;
    t.h[0] = __float2bfloat16(v.x); t.h[1] = __float2bfloat16(v.y);
    t.h[2] = __float2bfloat16(v.z); t.h[3] = __float2bfloat16(v.w);
    ((uint2*)out)[i] = t.v;
}

// w_xproj (96,2048) -> bf16 padded to (128,2048), rows 96..127 = 0
__global__ void __launch_bounds__(256) k_cast_pad_xproj(const float* __restrict__ in,
                                                        __hip_bfloat16* __restrict__ out) {
    int i = blockIdx.x * 256 + threadIdx.x;     // 65536 total
    int e = i >> 9, o = (i & 511) << 2;
    float4 v = make_float4(0.f, 0.f, 0.f, 0.f);
    if (e < 96) v = *(const float4*)&in[e * 2048 + o];
    B4 t;
    t.h[0] = __float2bfloat16(v.x); t.h[1] = __float2bfloat16(v.y);
    t.h[2] = __float2bfloat16(v.z); t.h[3] = __float2bfloat16(v.w);
    *(uint2*)&out[e * 2048 + o] = t.v;
}

// dt slice of x_dbl (ld 128, cols 0..63) -> bf16 (4096 x 64)
__global__ void __launch_bounds__(256) k_cast_dt(const float* __restrict__ x_dbl,
                                                 __hip_bfloat16* __restrict__ dt) {
    int i = blockIdx.x * 256 + threadIdx.x;     // 65536 total
    int m = i >> 4, o = (i & 15) << 2;
    float4 v = *(const float4*)&x_dbl[m * 128 + o];
    B4 t;
    t.h[0] = __float2bfloat16(v.x); t.h[1] = __float2bfloat16(v.y);
    t.h[2] = __float2bfloat16(v.z); t.h[3] = __float2bfloat16(v.w);
    *(uint2*)&dt[m * 64 + o] = t.v;
}

// ---------------------------------------------------------------------------
// NT GEMM: C[M,N] = A[M,K] * B[N,K]^T, bf16 in, f32 acc. 128x128 tile, BK=32,
// 4 waves (2x2 of 64x64), mfma_f32_16x16x32_bf16.
// EPI: 0 store bf16; 1 store f32; 2 softplus(x+ep[col]) f32; 3 x+ep[row*ldc+col] f32
template <int EPI>
__global__ void __launch_bounds__(256) k_gemm_nt(const __hip_bfloat16* __restrict__ A, int lda,
                                                 const __hip_bfloat16* __restrict__ B, int ldb,
                                                 float* __restrict__ Cf,
                                                 __hip_bfloat16* __restrict__ Cb, int ldc,
                                                 int K, const float* __restrict__ ep) {
    __shared__ short As[128 * 40];   // row stride 40 shorts = 80B (breaks pow2 bank stride)
    __shared__ short Bs[128 * 40];
    int tid = threadIdx.x;
    int lane = tid & 63, wid = tid >> 6;
    int row0 = blockIdx.y << 7, col0 = blockIdx.x << 7;
    int wm = (wid >> 1) << 6, wn = (wid & 1) << 6;
    int fr = lane & 15, ko = (lane >> 4) << 3;

    int ra0 = tid >> 2, oa = (tid & 3) << 3;   // piece tid: rows 0..63
    int ra1 = ra0 + 64;                         // piece tid+256: rows 64..127

    const short* Ag = (const short*)A;
    const short* Bg = (const short*)B;

    f32x4 acc[4][4] = {};

    for (int k0 = 0; k0 < K; k0 += 32) {
        __syncthreads();
        *(short8*)&As[ra0 * 40 + oa] = *(const short8*)&Ag[(size_t)(row0 + ra0) * lda + k0 + oa];
        *(short8*)&As[ra1 * 40 + oa] = *(const short8*)&Ag[(size_t)(row0 + ra1) * lda + k0 + oa];
        *(short8*)&Bs[ra0 * 40 + oa] = *(const short8*)&Bg[(size_t)(col0 + ra0) * ldb + k0 + oa];
        *(short8*)&Bs[ra1 * 40 + oa] = *(const short8*)&Bg[(size_t)(col0 + ra1) * ldb + k0 + oa];
        __syncthreads();
        short8 a[4], b[4];
#pragma unroll
        for (int mi = 0; mi < 4; ++mi) a[mi] = *(const short8*)&As[(wm + mi * 16 + fr) * 40 + ko];
#pragma unroll
        for (int ni = 0; ni < 4; ++ni) b[ni] = *(const short8*)&Bs[(wn + ni * 16 + fr) * 40 + ko];
#pragma unroll
        for (int mi = 0; mi < 4; ++mi)
#pragma unroll
            for (int ni = 0; ni < 4; ++ni)
                acc[mi][ni] = __builtin_amdgcn_mfma_f32_16x16x32_bf16(a[mi], b[ni], acc[mi][ni], 0, 0, 0);
    }

    int er = (lane >> 4) << 2;   // C/D: col = lane&15, row = (lane>>4)*4 + r  [m89]
    int ec = lane & 15;
#pragma unroll
    for (int mi = 0; mi < 4; ++mi)
#pragma unroll
        for (int ni = 0; ni < 4; ++ni)
#pragma unroll
            for (int r = 0; r < 4; ++r) {
                int gr = row0 + wm + mi * 16 + er + r;
                int gc = col0 + wn + ni * 16 + ec;
                size_t off = (size_t)gr * ldc + gc;
                float v = acc[mi][ni][r];
                if (EPI == 0) {
                    Cb[off] = __float2bfloat16(v);
                } else if (EPI == 1) {
                    Cf[off] = v;
                } else if (EPI == 2) {
                    float x = v + ep[gc];
                    Cf[off] = (x > 20.f) ? x : log1pf(__expf(x));
                } else {
                    Cf[off] = v + ep[off];
                }
            }
}

// ---------------------------------------------------------------------------
// causal depthwise conv (window 4) + bias + silu:  u_act = silu(conv(xz[:, :2048]))
__global__ void __launch_bounds__(256) k_conv(const __hip_bfloat16* __restrict__ xz,
                                              const float* __restrict__ cw,
                                              const float* __restrict__ cb,
                                              __hip_bfloat16* __restrict__ u_act) {
    int idx = blockIdx.x * 256 + threadIdx.x;   // 4096*256
    int m = idx >> 8, d = (idx & 255) << 3;
    int l = m & 1023;
    float acc[8];
#pragma unroll
    for (int j = 0; j < 8; ++j) acc[j] = cb[d + j];
#pragma unroll
    for (int k = 0; k < 4; ++k) {
        int lt = l - 3 + k;
        if (lt < 0) continue;
        B8 v;
        v.s = *(const short8*)(xz + (size_t)(m - 3 + k) * 4096 + d);
#pragma unroll
        for (int j = 0; j < 8; ++j)
            acc[j] += __bfloat162float(v.h[j]) * cw[(d + j) * 4 + k];
    }
    B8 o;
#pragma unroll
    for (int j = 0; j < 8; ++j) {
        float x = acc[j];
        o.h[j] = __float2bfloat16(x / (1.f + __expf(-x)));
    }
    *(short8*)(u_act + (size_t)m * 2048 + d) = o.s;
}

// ---------------------------------------------------------------------------
// Chunked parallel selective scan v2.  h_t = exp(dt*A)*h_{t-1} + dt*u*B_t.
// 32 chunks of 32 timesteps (4096 waves -> 4 waves/SIMD).  One thread owns one
// (b,d) channel's 16 states in registers.  B/C rows for the whole chunk are
// staged in LDS (broadcast ds_read_b128, immediate offsets) to kill the
// per-lane flat-load address arithmetic that bounded v1 (VALUBusy 55%).
// Summary layout: [b][c][s][d]  ->  ((b*32+c)*16+s)*2048 + d
__global__ void __launch_bounds__(256) k_scan_p1(const float* __restrict__ delta,
                                                 const __hip_bfloat16* __restrict__ u_act,
                                                 const float* __restrict__ x_dbl,
                                                 const float* __restrict__ a_log,
                                                 float* __restrict__ chP,
                                                 float* __restrict__ chS) {
    __shared__ __align__(16) float sBC[32][32];   // rows m0..m0+31, x_dbl cols 64..95
    int tid = threadIdx.x;
    int bid = blockIdx.x;            // 1024 = 4b x 32c x 8dg
    int bb = bid >> 8;
    int c  = (bid >> 3) & 31;
    int dg = bid & 7;
    int d  = (dg << 8) + tid;
    int m0 = (bb << 10) + (c << 5);
    {   // stage: 32 rows x 32 floats = 256 float4, one per thread
        int r = tid >> 3, q = (tid & 7) << 2;
        *(float4*)&sBC[r][q] = *(const float4*)&x_dbl[(size_t)(m0 + r) * 128 + 64 + q];
    }
    float A2[16], P[16], h[16];
#pragma unroll
    for (int s = 0; s < 16; ++s) {
        A2[s] = -__expf(a_log[d * 16 + s]) * 1.44269504f;   // pre-fold log2(e)
        P[s] = 1.f;
        h[s] = 0.f;
    }
    __syncthreads();
    for (int t = 0; t < 32; ++t) {
        int m = m0 + t;
        float dt = delta[(size_t)m * 2048 + d];
        float uv = __bfloat162float(u_act[(size_t)m * 2048 + d]);
        float x = dt * uv;
        f32x4 Bv0 = *(const f32x4*)&sBC[t][0];
        f32x4 Bv1 = *(const f32x4*)&sBC[t][4];
        f32x4 Bv2 = *(const f32x4*)&sBC[t][8];
        f32x4 Bv3 = *(const f32x4*)&sBC[t][12];
#pragma unroll
        for (int s = 0; s < 16; ++s) {
            float Bs_ = (s < 4) ? Bv0[s & 3] : (s < 8) ? Bv1[s & 3] : (s < 12) ? Bv2[s & 3] : Bv3[s & 3];
            float dA = exp2f(dt * A2[s]);
            P[s] *= dA;
            h[s] = fmaf(dA, h[s], x * Bs_);
        }
    }
    size_t base = (size_t)((bb * 32 + c) * 16) * 2048 + d;
#pragma unroll
    for (int s = 0; s < 16; ++s) {
        chP[base + (size_t)s * 2048] = P[s];
        chS[base + (size_t)s * 2048] = h[s];
    }
}

// one thread per (b,d,s): 32-step serial compose; chS becomes h_init per chunk
__global__ void __launch_bounds__(256) k_scan_p2(const float* __restrict__ chP,
                                                 float* __restrict__ chS) {
    int idx = blockIdx.x * 256 + threadIdx.x;   // 131072 = 4b x 16s x 2048d
    int bb = idx >> 15;
    int s  = (idx >> 11) & 15;
    int d  = idx & 2047;
    float h = 0.f;
    for (int c = 0; c < 32; ++c) {
        size_t off = (size_t)((bb * 32 + c) * 16 + s) * 2048 + d;
        float Pv = chP[off];
        float Sv = chS[off];
        chS[off] = h;                 // h_init for chunk c (state before chunk c)
        h = fmaf(Pv, h, Sv);
    }
}

__global__ void __launch_bounds__(256) k_scan_p3(const float* __restrict__ delta,
                                                 const __hip_bfloat16* __restrict__ u_act,
                                                 const __hip_bfloat16* __restrict__ xz,
                                                 const float* __restrict__ x_dbl,
                                                 const float* __restrict__ a_log,
                                                 const float* __restrict__ d_skip,
                                                 const float* __restrict__ hinit,
                                                 __hip_bfloat16* __restrict__ y) {
    __shared__ __align__(16) float sBC[32][32];
    int tid = threadIdx.x;
    int bid = blockIdx.x;            // 1024 = 4b x 32c x 8dg
    int bb = bid >> 8;
    int c  = (bid >> 3) & 31;
    int dg = bid & 7;
    int d  = (dg << 8) + tid;
    int m0 = (bb << 10) + (c << 5);
    {
        int r = tid >> 3, q = (tid & 7) << 2;
        *(float4*)&sBC[r][q] = *(const float4*)&x_dbl[(size_t)(m0 + r) * 128 + 64 + q];
    }
    float A2[16], h[16];
    size_t base = (size_t)((bb * 32 + c) * 16) * 2048 + d;
#pragma unroll
    for (int s = 0; s < 16; ++s) {
        A2[s] = -__expf(a_log[d * 16 + s]) * 1.44269504f;
        h[s] = hinit[base + (size_t)s * 2048];
    }
    float dsk = d_skip[d];
    __syncthreads();
    for (int t = 0; t < 32; ++t) {
        int m = m0 + t;
        float dt = delta[(size_t)m * 2048 + d];
        float uv = __bfloat162float(u_act[(size_t)m * 2048 + d]);
        float x = dt * uv;
        f32x4 Bv0 = *(const f32x4*)&sBC[t][0];
        f32x4 Bv1 = *(const f32x4*)&sBC[t][4];
        f32x4 Bv2 = *(const f32x4*)&sBC[t][8];
        f32x4 Bv3 = *(const f32x4*)&sBC[t][12];
        f32x4 Cv0 = *(const f32x4*)&sBC[t][16];
        f32x4 Cv1 = *(const f32x4*)&sBC[t][20];
        f32x4 Cv2 = *(const f32x4*)&sBC[t][24];
        f32x4 Cv3 = *(const f32x4*)&sBC[t][28];
        float yacc = 0.f;
#pragma unroll
        for (int s = 0; s < 16; ++s) {
            float Bs_ = (s < 4) ? Bv0[s & 3] : (s < 8) ? Bv1[s & 3] : (s < 12) ? Bv2[s & 3] : Bv3[s & 3];
            float Cs_ = (s < 4) ? Cv0[s & 3] : (s < 8) ? Cv1[s & 3] : (s < 12) ? Cv2[s & 3] : Cv3[s & 3];
            float dA = exp2f(dt * A2[s]);
            h[s] = fmaf(dA, h[s], x * Bs_);
            yacc = fmaf(h[s], Cs_, yacc);
        }
        float zv = __bfloat162float(xz[(size_t)m * 4096 + 2048 + d]);
        float yv = (yacc + uv * dsk) * (zv / (1.f + __expf(-zv)));
        y[(size_t)m * 2048 + d] = __float2bfloat16(yv);
    }
}

// ---------------------------------------------------------------------------
// layernorm in-place on d_out rows of 1024
__global__ void __launch_bounds__(256) k_ln(float* __restrict__ out,
                                            const float* __restrict__ g,
                                            const float* __restrict__ b) {
    int row = blockIdx.x;
    float* p = out + (size_t)row * 1024;
    int tid = threadIdx.x;
    float4 v = ((float4*)p)[tid];
    float s1 = v.x + v.y + v.z + v.w;
    float s2 = v.x * v.x + v.y * v.y + v.z * v.z + v.w * v.w;
    for (int off = 1; off < 64; off <<= 1) {
        s1 += __shfl_xor(s1, off, 64);
        s2 += __shfl_xor(s2, off, 64);
    }
    __shared__ float a1[4], a2[4];
    int wid = tid >> 6;
    if ((tid & 63) == 0) { a1[wid] = s1; a2[wid] = s2; }
    __syncthreads();
    s1 = a1[0] + a1[1] + a1[2] + a1[3];
    s2 = a2[0] + a2[1] + a2[2] + a2[3];
    float mean = s1 * (1.f / 1024.f);
    float var = s2 * (1.f / 1024.f) - mean * mean;
    float inv = rsqrtf(var + 1e-5f);
    float4 gv = ((const float4*)g)[tid];
    float4 bv = ((const float4*)b)[tid];
    v.x = (v.x - mean) * inv * gv.x + bv.x;
    v.y = (v.y - mean) * inv * gv.y + bv.y;
    v.z = (v.z - mean) * inv * gv.z + bv.z;
    v.w = (v.w - mean) * inv * gv.w + bv.w;
    ((float4*)p)[tid] = v;
}

// ---------------------------------------------------------------------------
extern "C" void kernel_launch(void* const* d_in, const int* in_sizes, int n_in,
                              void* d_out, int out_size, void* d_ws, size_t ws_size,
                              hipStream_t stream) {
    const float* query   = (const float*)d_in[0];
    const float* diff_ts = (const float*)d_in[1];
    const float* adaln_w = (const float*)d_in[2];
    const float* adaln_b = (const float*)d_in[3];
    const float* w_in    = (const float*)d_in[4];
    const float* conv_w  = (const float*)d_in[5];
    const float* conv_b  = (const float*)d_in[6];
    const float* w_xproj = (const float*)d_in[7];
    const float* w_dt    = (const float*)d_in[8];
    const float* b_dt    = (const float*)d_in[9];
    const float* a_log   = (const float*)d_in[10];
    const float* d_skip  = (const float*)d_in[11];
    const float* w_out   = (const float*)d_in[12];
    const float* ln_g    = (const float*)d_in[13];
    const float* ln_b    = (const float*)d_in[14];
    float* out = (float*)d_out;

    char* w = (char*)d_ws;
    auto alloc = [&](size_t bytes) -> char* {
        char* p = w;
        w += (bytes + 255) & ~(size_t)255;
        return p;
    };
    float*          mod     = (float*)         alloc((size_t)4 * 2048 * 4);
    __hip_bfloat16* aq      = (__hip_bfloat16*)alloc((size_t)4096 * 1024 * 2);
    __hip_bfloat16* w_in_b  = (__hip_bfloat16*)alloc((size_t)4096 * 1024 * 2);
    __hip_bfloat16* w_out_b = (__hip_bfloat16*)alloc((size_t)1024 * 2048 * 2);
    __hip_bfloat16* w_xp_b  = (__hip_bfloat16*)alloc((size_t)128 * 2048 * 2);
    __hip_bfloat16* w_dt_b  = (__hip_bfloat16*)alloc((size_t)2048 * 64 * 2);
    __hip_bfloat16* xz      = (__hip_bfloat16*)alloc((size_t)4096 * 4096 * 2);
    __hip_bfloat16* u_act   = (__hip_bfloat16*)alloc((size_t)4096 * 2048 * 2);
    float*          x_dbl   = (float*)         alloc((size_t)4096 * 128 * 4);
    __hip_bfloat16* dtb     = (__hip_bfloat16*)alloc((size_t)4096 * 64 * 2);
    float*          delta   = (float*)         alloc((size_t)4096 * 2048 * 4);
    __hip_bfloat16* yb      = (__hip_bfloat16*)alloc((size_t)4096 * 2048 * 2);
    float*          chP     = (float*)         alloc((size_t)4 * 32 * 16 * 2048 * 4);
    float*          chS     = (float*)         alloc((size_t)4 * 32 * 16 * 2048 * 4);

    k_adaln_mod<<<32, 256, 0, stream>>>(diff_ts, adaln_w, adaln_b, mod);
    k_modulate<<<4096, 256, 0, stream>>>(query, mod, aq);
    k_cast<<<4096, 256, 0, stream>>>(w_in, w_in_b, 4096 * 1024 / 4);
    k_cast<<<2048, 256, 0, stream>>>(w_out, w_out_b, 1024 * 2048 / 4);
    k_cast_pad_xproj<<<256, 256, 0, stream>>>(w_xproj, w_xp_b);
    k_cast<<<128, 256, 0, stream>>>(w_dt, w_dt_b, 2048 * 64 / 4);

    // xz = aq @ w_in^T   (M=4096, N=4096, K=1024) -> bf16
    k_gemm_nt<0><<<dim3(32, 32), 256, 0, stream>>>(aq, 1024, w_in_b, 1024,
                                                   nullptr, xz, 4096, 1024, nullptr);
    // conv + silu -> u_act
    k_conv<<<4096, 256, 0, stream>>>(xz, conv_w, conv_b, u_act);
    // x_dbl = u_act @ w_xprojP^T (M=4096, N=128(pad), K=2048) -> f32 ld 128
    k_gemm_nt<1><<<dim3(1, 32), 256, 0, stream>>>(u_act, 2048, w_xp_b, 2048,
                                                  x_dbl, nullptr, 128, 2048, nullptr);
    k_cast_dt<<<256, 256, 0, stream>>>(x_dbl, dtb);
    // delta = softplus(dt @ w_dt^T + b_dt) (M=4096, N=2048, K=64) -> f32
    k_gemm_nt<2><<<dim3(16, 32), 256, 0, stream>>>(dtb, 64, w_dt_b, 64,
                                                   delta, nullptr, 2048, 64, b_dt);
    // chunked parallel selective scan v2 -> yb (fused +u*d_skip, *silu(z))
    k_scan_p1<<<1024, 256, 0, stream>>>(delta, u_act, x_dbl, a_log, chP, chS);
    k_scan_p2<<<512, 256, 0, stream>>>(chP, chS);
    k_scan_p3<<<1024, 256, 0, stream>>>(delta, u_act, xz, x_dbl, a_log, d_skip, chS, yb);
    // out_pre = yb @ w_out^T + query (M=4096, N=1024, K=2048) -> f32 d_out
    k_gemm_nt<3><<<dim3(8, 32), 256, 0, stream>>>(yb, 2048, w_out_b, 2048,
                                                  out, nullptr, 1024, 2048, query);
    // layernorm in place
    k_ln<<<4096, 256, 0, stream>>>(out, ln_g, ln_b);
}

// Round 13
// 489.980 us; speedup vs baseline: 1.3765x; 1.0484x over previous
//
#include <hip/hip_runtime.h>
#include <hip/hip_bf16.h>

typedef __attribute__((ext_vector_type(8))) short short8;
typedef __attribute__((ext_vector_type(4))) float f32x4;

union B4 { __hip_bfloat16 h[4]; uint2 v; };
union B8 { __hip_bfloat16 h[8]; short8 s; };

// ---------------------------------------------------------------------------
// adaln: mod[b,e] = dot(silu(diff_ts[b,:]), adaln_w[e,:]) + adaln_b[e]
__global__ void __launch_bounds__(256) k_adaln_mod(const float* __restrict__ dts,
                                                   const float* __restrict__ w,
                                                   const float* __restrict__ b,
                                                   float* __restrict__ mod) {
    __shared__ float sd[1024];
    int bb = blockIdx.x >> 3;
    int e  = ((blockIdx.x & 7) << 8) + threadIdx.x;
    for (int i = threadIdx.x; i < 1024; i += 256) {
        float x = dts[bb * 1024 + i];
        sd[i] = x / (1.f + __expf(-x));
    }
    __syncthreads();
    const float* wr = w + (size_t)e * 1024;
    float acc = 0.f;
    for (int k = 0; k < 1024; k += 4) {
        float4 wv = *(const float4*)(wr + k);
        acc += wv.x * sd[k] + wv.y * sd[k + 1] + wv.z * sd[k + 2] + wv.w * sd[k + 3];
    }
    mod[bb * 2048 + e] = acc + b[e];
}

// aq = query*(1+scale)+shift  -> bf16
__global__ void __launch_bounds__(256) k_modulate(const float* __restrict__ q,
                                                  const float* __restrict__ mod,
                                                  __hip_bfloat16* __restrict__ aq) {
    int idx = blockIdx.x * 256 + threadIdx.x;   // 4096*256 total
    int m = idx >> 8, o = (idx & 255) << 2;
    int bb = m >> 10;
    float4 qv = *(const float4*)(q + (size_t)m * 1024 + o);
    float4 sc = *(const float4*)(mod + bb * 2048 + o);
    float4 sh = *(const float4*)(mod + bb * 2048 + 1024 + o);
    B4 t;
    t.h[0] = __float2bfloat16(qv.x * (1.f + sc.x) + sh.x);
    t.h[1] = __float2bfloat16(qv.y * (1.f + sc.y) + sh.y);
    t.h[2] = __float2bfloat16(qv.z * (1.f + sc.z) + sh.z);
    t.h[3] = __float2bfloat16(qv.w * (1.f + sc.w) + sh.w);
    *(uint2*)(aq + (size_t)m * 1024 + o) = t.v;
}

// generic f32 -> bf16 cast (n4 = n/4)
__global__ void __launch_bounds__(256) k_cast(const float* __restrict__ in,
                                              __hip_bfloat16* __restrict__ out, int n4) {
    int i = blockIdx.x * 256 + threadIdx.x;
    if (i >= n4) return;
    float4 v = ((const float4*)in)[i];
    B4 t;
    t.h[0] = __float2bfloat16(v.x); t.h[1] = __float2bfloat16(v.y);
    t.h[2] = __float2bfloat16(v.z); t.h[3] = __float2bfloat16(v.w);
    ((uint2*)out)[i] = t.v;
}

// w_xproj (96,2048) -> bf16 padded to (128,2048), rows 96..127 = 0
__global__ void __launch_bounds__(256) k_cast_pad_xproj(const float* __restrict__ in,
                                                        __hip_bfloat16* __restrict__ out) {
    int i = blockIdx.x * 256 + threadIdx.x;     // 65536 total
    int e = i >> 9, o = (i & 511) << 2;
    float4 v = make_float4(0.f, 0.f, 0.f, 0.f);
    if (e < 96) v = *(const float4*)&in[e * 2048 + o];
    B4 t;
    t.h[0] = __float2bfloat16(v.x); t.h[1] = __float2bfloat16(v.y);
    t.h[2] = __float2bfloat16(v.z); t.h[3] = __float2bfloat16(v.w);
    *(uint2*)&out[e * 2048 + o] = t.v;
}

// dt slice of x_dbl (ld 128, cols 0..63) -> bf16 (4096 x 64)
__global__ void __launch_bounds__(256) k_cast_dt(const float* __restrict__ x_dbl,
                                                 __hip_bfloat16* __restrict__ dt) {
    int i = blockIdx.x * 256 + threadIdx.x;     // 65536 total
    int m = i >> 4, o = (i & 15) << 2;
    float4 v = *(const float4*)&x_dbl[m * 128 + o];
    B4 t;
    t.h[0] = __float2bfloat16(v.x); t.h[1] = __float2bfloat16(v.y);
    t.h[2] = __float2bfloat16(v.z); t.h[3] = __float2bfloat16(v.w);
    *(uint2*)&dt[m * 64 + o] = t.v;
}

// ---------------------------------------------------------------------------
// NT GEMM: C[M,N] = A[M,K] * B[N,K]^T, bf16 in, f32 acc. 128x128 tile, BK=32,
// 4 waves (2x2 of 64x64), mfma_f32_16x16x32_bf16.
// EPI: 0 store bf16; 1 store f32; 2 softplus(x+ep[col]) f32; 3 x+ep[row*ldc+col] f32
template <int EPI>
__global__ void __launch_bounds__(256) k_gemm_nt(const __hip_bfloat16* __restrict__ A, int lda,
                                                 const __hip_bfloat16* __restrict__ B, int ldb,
                                                 float* __restrict__ Cf,
                                                 __hip_bfloat16* __restrict__ Cb, int ldc,
                                                 int K, const float* __restrict__ ep) {
    __shared__ short As[128 * 40];   // row stride 40 shorts = 80B (breaks pow2 bank stride)
    __shared__ short Bs[128 * 40];
    int tid = threadIdx.x;
    int lane = tid & 63, wid = tid >> 6;
    int row0 = blockIdx.y << 7, col0 = blockIdx.x << 7;
    int wm = (wid >> 1) << 6, wn = (wid & 1) << 6;
    int fr = lane & 15, ko = (lane >> 4) << 3;

    int ra0 = tid >> 2, oa = (tid & 3) << 3;   // piece tid: rows 0..63
    int ra1 = ra0 + 64;                         // piece tid+256: rows 64..127

    const short* Ag = (const short*)A;
    const short* Bg = (const short*)B;

    f32x4 acc[4][4] = {};

    for (int k0 = 0; k0 < K; k0 += 32) {
        __syncthreads();
        *(short8*)&As[ra0 * 40 + oa] = *(const short8*)&Ag[(size_t)(row0 + ra0) * lda + k0 + oa];
        *(short8*)&As[ra1 * 40 + oa] = *(const short8*)&Ag[(size_t)(row0 + ra1) * lda + k0 + oa];
        *(short8*)&Bs[ra0 * 40 + oa] = *(const short8*)&Bg[(size_t)(col0 + ra0) * ldb + k0 + oa];
        *(short8*)&Bs[ra1 * 40 + oa] = *(const short8*)&Bg[(size_t)(col0 + ra1) * ldb + k0 + oa];
        __syncthreads();
        short8 a[4], b[4];
#pragma unroll
        for (int mi = 0; mi < 4; ++mi) a[mi] = *(const short8*)&As[(wm + mi * 16 + fr) * 40 + ko];
#pragma unroll
        for (int ni = 0; ni < 4; ++ni) b[ni] = *(const short8*)&Bs[(wn + ni * 16 + fr) * 40 + ko];
#pragma unroll
        for (int mi = 0; mi < 4; ++mi)
#pragma unroll
            for (int ni = 0; ni < 4; ++ni)
                acc[mi][ni] = __builtin_amdgcn_mfma_f32_16x16x32_bf16(a[mi], b[ni], acc[mi][ni], 0, 0, 0);
    }

    int er = (lane >> 4) << 2;   // C/D: col = lane&15, row = (lane>>4)*4 + r  [m89]
    int ec = lane & 15;
#pragma unroll
    for (int mi = 0; mi < 4; ++mi)
#pragma unroll
        for (int ni = 0; ni < 4; ++ni)
#pragma unroll
            for (int r = 0; r < 4; ++r) {
                int gr = row0 + wm + mi * 16 + er + r;
                int gc = col0 + wn + ni * 16 + ec;
                size_t off = (size_t)gr * ldc + gc;
                float v = acc[mi][ni][r];
                if (EPI == 0) {
                    Cb[off] = __float2bfloat16(v);
                } else if (EPI == 1) {
                    Cf[off] = v;
                } else if (EPI == 2) {
                    float x = v + ep[gc];
                    Cf[off] = (x > 20.f) ? x : log1pf(__expf(x));
                } else {
                    Cf[off] = v + ep[off];
                }
            }
}

// ---------------------------------------------------------------------------
// causal depthwise conv (window 4) + bias + silu:  u_act = silu(conv(xz[:, :2048]))
// v2: float4-vectorized weight/bias loads. v1 used 40 per-lane SCALAR loads
// (cw/cb) whose addresses stride 8 channels per lane -> 64 cache lines per
// instruction -> TA serialization (VALUBusy 7.9%, 65us). Now 10 float4 loads.
__global__ void __launch_bounds__(256) k_conv(const __hip_bfloat16* __restrict__ xz,
                                              const float* __restrict__ cw,
                                              const float* __restrict__ cb,
                                              __hip_bfloat16* __restrict__ u_act) {
    int idx = blockIdx.x * 256 + threadIdx.x;   // 4096*256
    int m = idx >> 8, d = (idx & 255) << 3;
    int l = m & 1023;
    float W[8][4];
#pragma unroll
    for (int j = 0; j < 8; ++j) {
        float4 wv = *(const float4*)&cw[(d + j) * 4];   // per-lane contiguous 16B
        W[j][0] = wv.x; W[j][1] = wv.y; W[j][2] = wv.z; W[j][3] = wv.w;
    }
    float4 cb0 = *(const float4*)&cb[d];
    float4 cb1 = *(const float4*)&cb[d + 4];
    float acc[8] = {cb0.x, cb0.y, cb0.z, cb0.w, cb1.x, cb1.y, cb1.z, cb1.w};
#pragma unroll
    for (int k = 0; k < 4; ++k) {
        int lt = l - 3 + k;
        if (lt < 0) continue;
        B8 v;
        v.s = *(const short8*)(xz + (size_t)(m - 3 + k) * 4096 + d);
#pragma unroll
        for (int j = 0; j < 8; ++j)
            acc[j] += __bfloat162float(v.h[j]) * W[j][k];
    }
    B8 o;
#pragma unroll
    for (int j = 0; j < 8; ++j) {
        float x = acc[j];
        o.h[j] = __float2bfloat16(x / (1.f + __expf(-x)));
    }
    *(short8*)(u_act + (size_t)m * 2048 + d) = o.s;
}

// ---------------------------------------------------------------------------
// Chunked parallel selective scan v2.  h_t = exp(dt*A)*h_{t-1} + dt*u*B_t.
// 32 chunks of 32 timesteps (4096 waves -> 4 waves/SIMD).  One thread owns one
// (b,d) channel's 16 states in registers.  B/C rows for the whole chunk are
// staged in LDS (broadcast ds_read_b128, immediate offsets).
// Summary layout: [b][c][s][d]  ->  ((b*32+c)*16+s)*2048 + d
__global__ void __launch_bounds__(256) k_scan_p1(const float* __restrict__ delta,
                                                 const __hip_bfloat16* __restrict__ u_act,
                                                 const float* __restrict__ x_dbl,
                                                 const float* __restrict__ a_log,
                                                 float* __restrict__ chP,
                                                 float* __restrict__ chS) {
    __shared__ __align__(16) float sBC[32][32];   // rows m0..m0+31, x_dbl cols 64..95
    int tid = threadIdx.x;
    int bid = blockIdx.x;            // 1024 = 4b x 32c x 8dg
    int bb = bid >> 8;
    int c  = (bid >> 3) & 31;
    int dg = bid & 7;
    int d  = (dg << 8) + tid;
    int m0 = (bb << 10) + (c << 5);
    {   // stage: 32 rows x 32 floats = 256 float4, one per thread
        int r = tid >> 3, q = (tid & 7) << 2;
        *(float4*)&sBC[r][q] = *(const float4*)&x_dbl[(size_t)(m0 + r) * 128 + 64 + q];
    }
    float A2[16], P[16], h[16];
#pragma unroll
    for (int s = 0; s < 16; ++s) {
        A2[s] = -__expf(a_log[d * 16 + s]) * 1.44269504f;   // pre-fold log2(e)
        P[s] = 1.f;
        h[s] = 0.f;
    }
    __syncthreads();
    for (int t = 0; t < 32; ++t) {
        int m = m0 + t;
        float dt = delta[(size_t)m * 2048 + d];
        float uv = __bfloat162float(u_act[(size_t)m * 2048 + d]);
        float x = dt * uv;
        f32x4 Bv0 = *(const f32x4*)&sBC[t][0];
        f32x4 Bv1 = *(const f32x4*)&sBC[t][4];
        f32x4 Bv2 = *(const f32x4*)&sBC[t][8];
        f32x4 Bv3 = *(const f32x4*)&sBC[t][12];
#pragma unroll
        for (int s = 0; s < 16; ++s) {
            float Bs_ = (s < 4) ? Bv0[s & 3] : (s < 8) ? Bv1[s & 3] : (s < 12) ? Bv2[s & 3] : Bv3[s & 3];
            float dA = exp2f(dt * A2[s]);
            P[s] *= dA;
            h[s] = fmaf(dA, h[s], x * Bs_);
        }
    }
    size_t base = (size_t)((bb * 32 + c) * 16) * 2048 + d;
#pragma unroll
    for (int s = 0; s < 16; ++s) {
        chP[base + (size_t)s * 2048] = P[s];
        chS[base + (size_t)s * 2048] = h[s];
    }
}

// one thread per (b,d,s): 32-step serial compose; chS becomes h_init per chunk
__global__ void __launch_bounds__(256) k_scan_p2(const float* __restrict__ chP,
                                                 float* __restrict__ chS) {
    int idx = blockIdx.x * 256 + threadIdx.x;   // 131072 = 4b x 16s x 2048d
    int bb = idx >> 15;
    int s  = (idx >> 11) & 15;
    int d  = idx & 2047;
    float h = 0.f;
    for (int c = 0; c < 32; ++c) {
        size_t off = (size_t)((bb * 32 + c) * 16 + s) * 2048 + d;
        float Pv = chP[off];
        float Sv = chS[off];
        chS[off] = h;                 // h_init for chunk c (state before chunk c)
        h = fmaf(Pv, h, Sv);
    }
}

__global__ void __launch_bounds__(256) k_scan_p3(const float* __restrict__ delta,
                                                 const __hip_bfloat16* __restrict__ u_act,
                                                 const __hip_bfloat16* __restrict__ xz,
                                                 const float* __restrict__ x_dbl,
                                                 const float* __restrict__ a_log,
                                                 const float* __restrict__ d_skip,
                                                 const float* __restrict__ hinit,
                                                 __hip_bfloat16* __restrict__ y) {
    __shared__ __align__(16) float sBC[32][32];
    int tid = threadIdx.x;
    int bid = blockIdx.x;            // 1024 = 4b x 32c x 8dg
    int bb = bid >> 8;
    int c  = (bid >> 3) & 31;
    int dg = bid & 7;
    int d  = (dg << 8) + tid;
    int m0 = (bb << 10) + (c << 5);
    {
        int r = tid >> 3, q = (tid & 7) << 2;
        *(float4*)&sBC[r][q] = *(const float4*)&x_dbl[(size_t)(m0 + r) * 128 + 64 + q];
    }
    float A2[16], h[16];
    size_t base = (size_t)((bb * 32 + c) * 16) * 2048 + d;
#pragma unroll
    for (int s = 0; s < 16; ++s) {
        A2[s] = -__expf(a_log[d * 16 + s]) * 1.44269504f;
        h[s] = hinit[base + (size_t)s * 2048];
    }
    float dsk = d_skip[d];
    __syncthreads();
    for (int t = 0; t < 32; ++t) {
        int m = m0 + t;
        float dt = delta[(size_t)m * 2048 + d];
        float uv = __bfloat162float(u_act[(size_t)m * 2048 + d]);
        float x = dt * uv;
        f32x4 Bv0 = *(const f32x4*)&sBC[t][0];
        f32x4 Bv1 = *(const f32x4*)&sBC[t][4];
        f32x4 Bv2 = *(const f32x4*)&sBC[t][8];
        f32x4 Bv3 = *(const f32x4*)&sBC[t][12];
        f32x4 Cv0 = *(const f32x4*)&sBC[t][16];
        f32x4 Cv1 = *(const f32x4*)&sBC[t][20];
        f32x4 Cv2 = *(const f32x4*)&sBC[t][24];
        f32x4 Cv3 = *(const f32x4*)&sBC[t][28];
        float yacc = 0.f;
#pragma unroll
        for (int s = 0; s < 16; ++s) {
            float Bs_ = (s < 4) ? Bv0[s & 3] : (s < 8) ? Bv1[s & 3] : (s < 12) ? Bv2[s & 3] : Bv3[s & 3];
            float Cs_ = (s < 4) ? Cv0[s & 3] : (s < 8) ? Cv1[s & 3] : (s < 12) ? Cv2[s & 3] : Cv3[s & 3];
            float dA = exp2f(dt * A2[s]);
            h[s] = fmaf(dA, h[s], x * Bs_);
            yacc = fmaf(h[s], Cs_, yacc);
        }
        float zv = __bfloat162float(xz[(size_t)m * 4096 + 2048 + d]);
        float yv = (yacc + uv * dsk) * (zv / (1.f + __expf(-zv)));
        y[(size_t)m * 2048 + d] = __float2bfloat16(yv);
    }
}

// ---------------------------------------------------------------------------
// layernorm in-place on d_out rows of 1024
__global__ void __launch_bounds__(256) k_ln(float* __restrict__ out,
                                            const float* __restrict__ g,
                                            const float* __restrict__ b) {
    int row = blockIdx.x;
    float* p = out + (size_t)row * 1024;
    int tid = threadIdx.x;
    float4 v = ((float4*)p)[tid];
    float s1 = v.x + v.y + v.z + v.w;
    float s2 = v.x * v.x + v.y * v.y + v.z * v.z + v.w * v.w;
    for (int off = 1; off < 64; off <<= 1) {
        s1 += __shfl_xor(s1, off, 64);
        s2 += __shfl_xor(s2, off, 64);
    }
    __shared__ float a1[4], a2[4];
    int wid = tid >> 6;
    if ((tid & 63) == 0) { a1[wid] = s1; a2[wid] = s2; }
    __syncthreads();
    s1 = a1[0] + a1[1] + a1[2] + a1[3];
    s2 = a2[0] + a2[1] + a2[2] + a2[3];
    float mean = s1 * (1.f / 1024.f);
    float var = s2 * (1.f / 1024.f) - mean * mean;
    float inv = rsqrtf(var + 1e-5f);
    float4 gv = ((const float4*)g)[tid];
    float4 bv = ((const float4*)b)[tid];
    v.x = (v.x - mean) * inv * gv.x + bv.x;
    v.y = (v.y - mean) * inv * gv.y + bv.y;
    v.z = (v.z - mean) * inv * gv.z + bv.z;
    v.w = (v.w - mean) * inv * gv.w + bv.w;
    ((float4*)p)[tid] = v;
}

// ---------------------------------------------------------------------------
extern "C" void kernel_launch(void* const* d_in, const int* in_sizes, int n_in,
                              void* d_out, int out_size, void* d_ws, size_t ws_size,
                              hipStream_t stream) {
    const float* query   = (const float*)d_in[0];
    const float* diff_ts = (const float*)d_in[1];
    const float* adaln_w = (const float*)d_in[2];
    const float* adaln_b = (const float*)d_in[3];
    const float* w_in    = (const float*)d_in[4];
    const float* conv_w  = (const float*)d_in[5];
    const float* conv_b  = (const float*)d_in[6];
    const float* w_xproj = (const float*)d_in[7];
    const float* w_dt    = (const float*)d_in[8];
    const float* b_dt    = (const float*)d_in[9];
    const float* a_log   = (const float*)d_in[10];
    const float* d_skip  = (const float*)d_in[11];
    const float* w_out   = (const float*)d_in[12];
    const float* ln_g    = (const float*)d_in[13];
    const float* ln_b    = (const float*)d_in[14];
    float* out = (float*)d_out;

    char* w = (char*)d_ws;
    auto alloc = [&](size_t bytes) -> char* {
        char* p = w;
        w += (bytes + 255) & ~(size_t)255;
        return p;
    };
    float*          mod     = (float*)         alloc((size_t)4 * 2048 * 4);
    __hip_bfloat16* aq      = (__hip_bfloat16*)alloc((size_t)4096 * 1024 * 2);
    __hip_bfloat16* w_in_b  = (__hip_bfloat16*)alloc((size_t)4096 * 1024 * 2);
    __hip_bfloat16* w_out_b = (__hip_bfloat16*)alloc((size_t)1024 * 2048 * 2);
    __hip_bfloat16* w_xp_b  = (__hip_bfloat16*)alloc((size_t)128 * 2048 * 2);
    __hip_bfloat16* w_dt_b  = (__hip_bfloat16*)alloc((size_t)2048 * 64 * 2);
    __hip_bfloat16* xz      = (__hip_bfloat16*)alloc((size_t)4096 * 4096 * 2);
    __hip_bfloat16* u_act   = (__hip_bfloat16*)alloc((size_t)4096 * 2048 * 2);
    float*          x_dbl   = (float*)         alloc((size_t)4096 * 128 * 4);
    __hip_bfloat16* dtb     = (__hip_bfloat16*)alloc((size_t)4096 * 64 * 2);
    float*          delta   = (float*)         alloc((size_t)4096 * 2048 * 4);
    __hip_bfloat16* yb      = (__hip_bfloat16*)alloc((size_t)4096 * 2048 * 2);
    float*          chP     = (float*)         alloc((size_t)4 * 32 * 16 * 2048 * 4);
    float*          chS     = (float*)         alloc((size_t)4 * 32 * 16 * 2048 * 4);

    k_adaln_mod<<<32, 256, 0, stream>>>(diff_ts, adaln_w, adaln_b, mod);
    k_modulate<<<4096, 256, 0, stream>>>(query, mod, aq);
    k_cast<<<4096, 256, 0, stream>>>(w_in, w_in_b, 4096 * 1024 / 4);
    k_cast<<<2048, 256, 0, stream>>>(w_out, w_out_b, 1024 * 2048 / 4);
    k_cast_pad_xproj<<<256, 256, 0, stream>>>(w_xproj, w_xp_b);
    k_cast<<<128, 256, 0, stream>>>(w_dt, w_dt_b, 2048 * 64 / 4);

    // xz = aq @ w_in^T   (M=4096, N=4096, K=1024) -> bf16
    k_gemm_nt<0><<<dim3(32, 32), 256, 0, stream>>>(aq, 1024, w_in_b, 1024,
                                                   nullptr, xz, 4096, 1024, nullptr);
    // conv + silu -> u_act
    k_conv<<<4096, 256, 0, stream>>>(xz, conv_w, conv_b, u_act);
    // x_dbl = u_act @ w_xprojP^T (M=4096, N=128(pad), K=2048) -> f32 ld 128
    k_gemm_nt<1><<<dim3(1, 32), 256, 0, stream>>>(u_act, 2048, w_xp_b, 2048,
                                                  x_dbl, nullptr, 128, 2048, nullptr);
    k_cast_dt<<<256, 256, 0, stream>>>(x_dbl, dtb);
    // delta = softplus(dt @ w_dt^T + b_dt) (M=4096, N=2048, K=64) -> f32
    k_gemm_nt<2><<<dim3(16, 32), 256, 0, stream>>>(dtb, 64, w_dt_b, 64,
                                                   delta, nullptr, 2048, 64, b_dt);
    // chunked parallel selective scan v2 -> yb (fused +u*d_skip, *silu(z))
    k_scan_p1<<<1024, 256, 0, stream>>>(delta, u_act, x_dbl, a_log, chP, chS);
    k_scan_p2<<<512, 256, 0, stream>>>(chP, chS);
    k_scan_p3<<<1024, 256, 0, stream>>>(delta, u_act, xz, x_dbl, a_log, d_skip, chS, yb);
    // out_pre = yb @ w_out^T + query (M=4096, N=1024, K=2048) -> f32 d_out
    k_gemm_nt<3><<<dim3(8, 32), 256, 0, stream>>>(yb, 2048, w_out_b, 2048,
                                                  out, nullptr, 1024, 2048, query);
    // layernorm in place
    k_ln<<<4096, 256, 0, stream>>>(out, ln_g, ln_b);
}